// Round 3
// baseline (1383.917 us; speedup 1.0000x reference)
//
#include <hip/hip_runtime.h>

#define NN 150000
#define EE 600000
#define HH 4
#define CC 64
#define GG 4096
#define INF 9

__device__ __forceinline__ float lrelu(float a){ return a > 0.f ? a : 0.2f*a; }

// ---------------- CSR build ----------------
__global__ __launch_bounds__(256) void k_count(const int* __restrict__ dst, int* __restrict__ deg){
  int e = blockIdx.x*256 + threadIdx.x;
  if (e < EE) atomicAdd(&deg[dst[e]], 1);
}

__global__ __launch_bounds__(256) void k_scan1(const int* __restrict__ deg, int* __restrict__ excl, int* __restrict__ bsum){
  __shared__ int s[256];
  int tid = threadIdx.x, gid = blockIdx.x*256 + tid;
  int v = (gid < NN) ? deg[gid] : 0;
  s[tid] = v; __syncthreads();
  for (int off = 1; off < 256; off <<= 1){
    int t = (tid >= off) ? s[tid-off] : 0; __syncthreads();
    s[tid] += t; __syncthreads();
  }
  if (gid < NN) excl[gid] = s[tid] - v;
  if (tid == 255) bsum[blockIdx.x] = s[255];
}

__global__ __launch_bounds__(1024) void k_scan2(int* __restrict__ bsum, int nb){
  __shared__ int s[1024];
  int tid = threadIdx.x;
  int v = (tid < nb) ? bsum[tid] : 0;
  s[tid] = v; __syncthreads();
  for (int off = 1; off < 1024; off <<= 1){
    int t = (tid >= off) ? s[tid-off] : 0; __syncthreads();
    s[tid] += t; __syncthreads();
  }
  if (tid < nb) bsum[tid] = s[tid] - v;
}

__global__ __launch_bounds__(256) void k_scan3(int* __restrict__ rp, const int* __restrict__ bsum){
  int gid = blockIdx.x*256 + threadIdx.x;
  if (gid < NN) rp[gid] += bsum[blockIdx.x];
  if (gid == 0) rp[NN] = EE;
}

__global__ __launch_bounds__(256) void k_fill(const int* __restrict__ src, const int* __restrict__ dst,
                                              const int* __restrict__ rp, int* __restrict__ fill,
                                              int* __restrict__ col){
  int e = blockIdx.x*256 + threadIdx.x;
  if (e < EE){
    int d = dst[e];
    int pos = rp[d] + atomicAdd(&fill[d], 1);
    col[pos] = src[e];
  }
}

__global__ __launch_bounds__(256) void k_gstart(const int* __restrict__ batch, int* __restrict__ gstart){
  int g = blockIdx.x*256 + threadIdx.x;
  if (g > GG) return;
  int lo = 0, hi = NN;
  while (lo < hi){ int mid = (lo+hi) >> 1; if (batch[mid] < g) lo = mid+1; else hi = mid; }
  gstart[g] = lo;
}

// ---------------- fold weights ----------------
// Wa0[k*8+j]  (k<9):  sum_c g0W[k][h*64+c]*a[h][c], h=j&3, a=asrc(j<4)/adst(j>=4)
// Wa[i][k*8+j](k<64): likewise for gat layers
// Wstk0[(h*9+c)*64+j]   = 0.25*g0W[c][h*64+j]   (36x64)
// Wstk[i][(h*64+c)*64+j]= 0.25*gW[i][c][h*64+j] (256x64)
__global__ __launch_bounds__(256) void k_fold(const float* __restrict__ g0W, const float* __restrict__ g0as,
    const float* __restrict__ g0ad, const float* __restrict__ gW, const float* __restrict__ gas,
    const float* __restrict__ gad, float* __restrict__ Wa0, float* __restrict__ Wa,
    float* __restrict__ Wstk0, float* __restrict__ Wstk){
  const int OFF1 = 72, OFF2 = OFF1 + 1536, OFF3 = OFF2 + 2304, OFF4 = OFF3 + 49152;
  int t = blockIdx.x*256 + threadIdx.x;
  if (t < OFF1){
    int k = t >> 3, j = t & 7, h = j & 3;
    const float* a = (j < 4) ? g0as : g0ad;
    float s = 0.f;
    for (int c = 0; c < 64; c++) s += g0W[k*256 + h*64 + c] * a[h*64 + c];
    Wa0[t] = s;
  } else if (t < OFF2){
    int u = t - OFF1;
    int i = u / 512, r = u % 512, k = r >> 3, j = r & 7, h = j & 3;
    const float* a = ((j < 4) ? gas : gad) + (size_t)i*256;
    float s = 0.f;
    for (int c = 0; c < 64; c++) s += gW[(size_t)i*16384 + k*256 + h*64 + c] * a[h*64 + c];
    Wa[u] = s;
  } else if (t < OFF3){
    int u = t - OFF2;           // u = k*64 + j, k = h*9+c
    int k = u >> 6, j = u & 63;
    int h = k / 9, c = k - h*9;
    Wstk0[u] = 0.25f * g0W[c*256 + h*64 + j];
  } else if (t < OFF4){
    int u = t - OFF3;           // u = i*16384 + k*64 + j, k = h*64+c
    int i = u >> 14, r = u & 16383;
    int k = r >> 6, j = r & 63;
    int h = k >> 6, c = k & 63;
    Wstk[u] = 0.25f * gW[(size_t)i*16384 + c*256 + h*64 + j];
  }
}

// ---------------- logits: lg[n*8+j] = hin[n,:] @ Wa[:,j] ----------------
template<int K>
__global__ __launch_bounds__(256) void k_logits(const float* __restrict__ hin, const float* __restrict__ Wa,
                                                float* __restrict__ lg){
  int idx = blockIdx.x*256 + threadIdx.x;
  int node = idx >> 3, j = idx & 7;
  if (node >= NN) return;
  const float* r = hin + (size_t)node*K;
  float s = 0.f;
  #pragma unroll
  for (int k = 0; k < K; k++) s += r[k] * Wa[k*8 + j];
  lg[(size_t)node*8 + j] = s;
}

// ---------------- aggregate RAW features per head (wave per node) ----------------
// agg[n][h*KF+c] = (1/denom_h) * sum_{e into n (incl self)} exp(lrelu(es[s][h]+ed[n][h])) * hin[s][c]
template<int KF>
__global__ __launch_bounds__(256) void k_aggA(const float* __restrict__ hin, const float* __restrict__ lg,
     const int* __restrict__ rp, const int* __restrict__ col, float* __restrict__ agg){
  int node = (blockIdx.x*256 + threadIdx.x) >> 6;
  int lane = threadIdx.x & 63;
  if (node >= NN) return;
  node = __builtin_amdgcn_readfirstlane(node);
  int rb = rp[node], re = rp[node+1];
  float4 esn = *(const float4*)(lg + (size_t)node*8);
  float4 edt = *(const float4*)(lg + (size_t)node*8 + 4);
  float edn[4] = {edt.x, edt.y, edt.z, edt.w};

  float den[4], acc[4];
  {
    float xv = (lane < KF) ? hin[(size_t)node*KF + lane] : 0.f;
    float a[4] = {esn.x, esn.y, esn.z, esn.w};
    #pragma unroll
    for (int h = 0; h < 4; h++){
      float ex = __expf(lrelu(a[h] + edn[h]));
      den[h] = ex; acc[h] = ex * xv;
    }
  }

  int e = rb;
  if (e < re){
    int sA = col[e];
    float4 tA = *(const float4*)(lg + (size_t)sA*8);
    float xA = (lane < KF) ? hin[(size_t)sA*KF + lane] : 0.f;
    for (; e < re; ){
      int en = e + 1;
      int sB = (en < re) ? col[en] : sA;
      float4 tB = *(const float4*)(lg + (size_t)sB*8);
      float xB = (lane < KF) ? hin[(size_t)sB*KF + lane] : 0.f;
      float ex0 = __expf(lrelu(tA.x + edn[0])); den[0] += ex0; acc[0] += ex0 * xA;
      float ex1 = __expf(lrelu(tA.y + edn[1])); den[1] += ex1; acc[1] += ex1 * xA;
      float ex2 = __expf(lrelu(tA.z + edn[2])); den[2] += ex2; acc[2] += ex2 * xA;
      float ex3 = __expf(lrelu(tA.w + edn[3])); den[3] += ex3; acc[3] += ex3 * xA;
      tA = tB; xA = xB;
      e = en;
    }
  }

  if (lane < KF){
    float* ap = agg + (size_t)node*(4*KF) + lane;
    #pragma unroll
    for (int h = 0; h < 4; h++) ap[h*KF] = acc[h] / den[h];
  }
}

// ---------------- transform + epilogue: hout = agg @ Ws (+bias, BN, ELU, +res) ----------------
// 64 nodes/block, 256 threads: wave w -> cols w*16..+15 (W rows via SGPR), lane -> node.
template<int KK>
__global__ __launch_bounds__(256) void k_gemmB(const float* __restrict__ agg, const float* __restrict__ Ws,
    const float* __restrict__ bias, const float* __restrict__ gma, const float* __restrict__ bta,
    const float* __restrict__ mea, const float* __restrict__ var,
    const float* __restrict__ hres, float* __restrict__ hout){
  constexpr int PK = (KK == 256) ? 256 : 37;              // stride (256: XOR swizzle; 37: pad)
  constexpr int LSZ = (KK == 256) ? 64*256 : 64*65;       // transpose tile needs 64*65
  __shared__ float xs[LSZ];
  int t = threadIdx.x;
  int base = blockIdx.x * 64;

  // stage agg tile (scalar, coalesced global reads)
  for (int i = t; i < 64*KK; i += 256){
    int nd = i / KK, k = i - nd*KK;
    float v = (base + nd < NN) ? agg[(size_t)base*KK + i] : 0.f;
    int a = (KK == 256) ? (nd*256 + (k ^ (nd & 31))) : (nd*PK + k);
    xs[a] = v;
  }
  __syncthreads();

  int wv = __builtin_amdgcn_readfirstlane((t >> 6) * 16); // col base (wave-uniform)
  int lane = t & 63;
  int sw = lane & 31;
  const float* Wp = Ws + wv;
  float acc[16];
  #pragma unroll
  for (int c = 0; c < 16; c++) acc[c] = 0.f;
  #pragma unroll 4
  for (int k = 0; k < KK; k++){
    float xv = xs[(KK == 256) ? (lane*256 + (k ^ sw)) : (lane*PK + k)];
    const float* wr = Wp + k*64;
    float4 wa = ((const float4*)wr)[0];
    float4 wb = ((const float4*)wr)[1];
    float4 wc = ((const float4*)wr)[2];
    float4 wd = ((const float4*)wr)[3];
    acc[0] += xv*wa.x; acc[1] += xv*wa.y; acc[2]  += xv*wa.z; acc[3]  += xv*wa.w;
    acc[4] += xv*wb.x; acc[5] += xv*wb.y; acc[6]  += xv*wb.z; acc[7]  += xv*wb.w;
    acc[8] += xv*wc.x; acc[9] += xv*wc.y; acc[10] += xv*wc.z; acc[11] += xv*wc.w;
    acc[12]+= xv*wd.x; acc[13]+= xv*wd.y; acc[14] += xv*wd.z; acc[15] += xv*wd.w;
  }
  __syncthreads();
  #pragma unroll
  for (int c = 0; c < 16; c++) xs[lane*65 + wv + c] = acc[c];
  __syncthreads();

  for (int i = t; i < 64*64; i += 256){
    int nd = i >> 6, j = i & 63;
    int node = base + nd;
    if (node < NN){
      float o = xs[nd*65 + j] + bias[j];
      o = (o - mea[j]) * rsqrtf(var[j] + 1e-5f) * gma[j] + bta[j];
      o = o > 0.f ? o : (__expf(o) - 1.f);
      if (hres) o += hres[(size_t)node*64 + j];
      hout[(size_t)node*64 + j] = o;
    }
  }
}

// ---------------- pooling ----------------
__global__ __launch_bounds__(64) void k_pool(const float* __restrict__ h, const int* __restrict__ gstart,
                                             float* __restrict__ pooled){
  int g = blockIdx.x; int lane = threadIdx.x;
  int beg = gstart[g], end = gstart[g+1];
  float acc = 0.f;
  for (int n = beg; n < end; n++) acc += h[(size_t)n*64 + lane];
  float cnt = (float)(end - beg);
  pooled[(size_t)g*64 + lane] = acc / fmaxf(cnt, 1.f);
}

// ---------------- output MLP ----------------
__global__ __launch_bounds__(256) void k_mlp(const float* __restrict__ pooled, const float* __restrict__ W1,
                                             const float* __restrict__ b1, const float* __restrict__ W2,
                                             const float* __restrict__ b2, float* __restrict__ out){
  int g = blockIdx.x*256 + threadIdx.x;
  if (g >= GG) return;
  const float* p = pooled + (size_t)g*64;
  float o = 0.f;
  for (int j = 0; j < 32; j++){
    float z = b1[j];
    for (int c = 0; c < 64; c++) z += p[c] * W1[c*32 + j];
    z = z > 0.f ? z : (__expf(z) - 1.f);
    o += z * W2[j];
  }
  out[g] = o + b2[0];
}

extern "C" void kernel_launch(void* const* d_in, const int* in_sizes, int n_in,
                              void* d_out, int out_size, void* d_ws, size_t ws_size,
                              hipStream_t stream) {
  const float* x    = (const float*)d_in[0];
  const int*   ei   = (const int*)d_in[1];
  const int*   batch= (const int*)d_in[2];
  const float* g0W  = (const float*)d_in[3];
  const float* g0as = (const float*)d_in[4];
  const float* g0ad = (const float*)d_in[5];
  const float* g0b  = (const float*)d_in[6];
  const float* bn0g = (const float*)d_in[7];
  const float* bn0b = (const float*)d_in[8];
  const float* bn0m = (const float*)d_in[9];
  const float* bn0v = (const float*)d_in[10];
  const float* gW   = (const float*)d_in[11];
  const float* gas  = (const float*)d_in[12];
  const float* gad  = (const float*)d_in[13];
  const float* gb   = (const float*)d_in[14];
  const float* bng  = (const float*)d_in[15];
  const float* bnb  = (const float*)d_in[16];
  const float* bnm  = (const float*)d_in[17];
  const float* bnv  = (const float*)d_in[18];
  const float* W1   = (const float*)d_in[19];
  const float* b1   = (const float*)d_in[20];
  const float* W2   = (const float*)d_in[21];
  const float* b2   = (const float*)d_in[22];
  float* out = (float*)d_out;
  (void)in_sizes; (void)n_in; (void)out_size; (void)ws_size;

  char* base = (char*)d_ws; size_t off = 0;
  auto alloc = [&](size_t b)->void*{ void* p = base + off; off = (off + b + 255) & ~(size_t)255; return p; };
  float* agg    = (float*)alloc((size_t)NN*256*4);   // 153.6 MB (also holds [N,36] for layer 0)
  float* h_cur  = (float*)alloc((size_t)NN*64*4);    // 38.4 MB
  float* lg     = (float*)alloc((size_t)NN*8*4);     // 4.8 MB
  int*   deg    = (int*)alloc((size_t)NN*4);
  int*   fill   = (int*)alloc((size_t)NN*4);
  int*   rp     = (int*)alloc((size_t)(NN+1)*4);
  int*   col    = (int*)alloc((size_t)EE*4);
  int*   bsum   = (int*)alloc(1024*4);
  int*   gstart = (int*)alloc((size_t)(GG+1)*4);
  float* pooled = (float*)alloc((size_t)GG*64*4);
  float* Wa0    = (float*)alloc((size_t)72*4);
  float* Wa     = (float*)alloc((size_t)1536*4);
  float* Wstk0  = (float*)alloc((size_t)2304*4);
  float* Wstk   = (float*)alloc((size_t)49152*4);

  const int* esrc = ei;
  const int* edst = ei + EE;

  hipMemsetAsync(deg, 0, (size_t)NN*4, stream);
  hipMemsetAsync(fill, 0, (size_t)NN*4, stream);

  int nb1 = (NN + 255)/256;
  k_count<<<(EE+255)/256, 256, 0, stream>>>(edst, deg);
  k_scan1<<<nb1, 256, 0, stream>>>(deg, rp, bsum);
  k_scan2<<<1, 1024, 0, stream>>>(bsum, nb1);
  k_scan3<<<nb1, 256, 0, stream>>>(rp, bsum);
  k_fill<<<(EE+255)/256, 256, 0, stream>>>(esrc, edst, rp, fill, col);
  k_gstart<<<(GG+256)/256, 256, 0, stream>>>(batch, gstart);
  k_fold<<<208, 256, 0, stream>>>(g0W, g0as, g0ad, gW, gas, gad, Wa0, Wa, Wstk0, Wstk);

  int nlog  = (NN*8 + 255)/256;   // 4688
  int nwave = NN/4;               // 37500
  int ngB   = (NN + 63)/64;       // 2344

  // layer 0
  k_logits<INF><<<nlog, 256, 0, stream>>>(x, Wa0, lg);
  k_aggA<INF><<<nwave, 256, 0, stream>>>(x, lg, rp, col, agg);
  k_gemmB<4*INF><<<ngB, 256, 0, stream>>>(agg, Wstk0, g0b, bn0g, bn0b, bn0m, bn0v,
                                          nullptr, h_cur);
  // layers 1..3
  for (int i = 0; i < 3; i++){
    k_logits<CC><<<nlog, 256, 0, stream>>>(h_cur, Wa + (size_t)i*512, lg);
    k_aggA<CC><<<nwave, 256, 0, stream>>>(h_cur, lg, rp, col, agg);
    k_gemmB<256><<<ngB, 256, 0, stream>>>(agg, Wstk + (size_t)i*16384, gb + (size_t)i*64,
                                          bng + (size_t)i*64, bnb + (size_t)i*64,
                                          bnm + (size_t)i*64, bnv + (size_t)i*64,
                                          h_cur, h_cur);
  }

  k_pool<<<GG, 64, 0, stream>>>(h_cur, gstart, pooled);
  k_mlp<<<(GG+255)/256, 256, 0, stream>>>(pooled, W1, b1, W2, b2, out);
}

// Round 4
// 767.114 us; speedup vs baseline: 1.8041x; 1.8041x over previous
//
#include <hip/hip_runtime.h>

#define NN 150000
#define EE 600000
#define HH 4
#define CC 64
#define GG 4096
#define INF 9

__device__ __forceinline__ float lrelu(float a){ return a > 0.f ? a : 0.2f*a; }

// ---------------- CSR build ----------------
__global__ __launch_bounds__(256) void k_count(const int* __restrict__ dst, int* __restrict__ deg){
  int e = blockIdx.x*256 + threadIdx.x;
  if (e < EE) atomicAdd(&deg[dst[e]], 1);
}

__global__ __launch_bounds__(256) void k_scan1(const int* __restrict__ deg, int* __restrict__ excl, int* __restrict__ bsum){
  __shared__ int s[256];
  int tid = threadIdx.x, gid = blockIdx.x*256 + tid;
  int v = (gid < NN) ? deg[gid] : 0;
  s[tid] = v; __syncthreads();
  for (int off = 1; off < 256; off <<= 1){
    int t = (tid >= off) ? s[tid-off] : 0; __syncthreads();
    s[tid] += t; __syncthreads();
  }
  if (gid < NN) excl[gid] = s[tid] - v;
  if (tid == 255) bsum[blockIdx.x] = s[255];
}

__global__ __launch_bounds__(1024) void k_scan2(int* __restrict__ bsum, int nb){
  __shared__ int s[1024];
  int tid = threadIdx.x;
  int v = (tid < nb) ? bsum[tid] : 0;
  s[tid] = v; __syncthreads();
  for (int off = 1; off < 1024; off <<= 1){
    int t = (tid >= off) ? s[tid-off] : 0; __syncthreads();
    s[tid] += t; __syncthreads();
  }
  if (tid < nb) bsum[tid] = s[tid] - v;
}

__global__ __launch_bounds__(256) void k_scan3(int* __restrict__ rp, const int* __restrict__ bsum){
  int gid = blockIdx.x*256 + threadIdx.x;
  if (gid < NN) rp[gid] += bsum[blockIdx.x];
  if (gid == 0) rp[NN] = EE;
}

__global__ __launch_bounds__(256) void k_fill(const int* __restrict__ src, const int* __restrict__ dst,
                                              const int* __restrict__ rp, int* __restrict__ fill,
                                              int* __restrict__ col){
  int e = blockIdx.x*256 + threadIdx.x;
  if (e < EE){
    int d = dst[e];
    int pos = rp[d] + atomicAdd(&fill[d], 1);
    col[pos] = src[e];
  }
}

__global__ __launch_bounds__(256) void k_gstart(const int* __restrict__ batch, int* __restrict__ gstart){
  int g = blockIdx.x*256 + threadIdx.x;
  if (g > GG) return;
  int lo = 0, hi = NN;
  while (lo < hi){ int mid = (lo+hi) >> 1; if (batch[mid] < g) lo = mid+1; else hi = mid; }
  gstart[g] = lo;
}

// ---------------- fold weights ----------------
__global__ __launch_bounds__(256) void k_fold(const float* __restrict__ g0W, const float* __restrict__ g0as,
    const float* __restrict__ g0ad, const float* __restrict__ gW, const float* __restrict__ gas,
    const float* __restrict__ gad, float* __restrict__ Wa0, float* __restrict__ Wa,
    float* __restrict__ Wstk0, float* __restrict__ Wstk){
  const int OFF1 = 72, OFF2 = OFF1 + 1536, OFF3 = OFF2 + 2304, OFF4 = OFF3 + 49152;
  int t = blockIdx.x*256 + threadIdx.x;
  if (t < OFF1){
    int k = t >> 3, j = t & 7, h = j & 3;
    const float* a = (j < 4) ? g0as : g0ad;
    float s = 0.f;
    for (int c = 0; c < 64; c++) s += g0W[k*256 + h*64 + c] * a[h*64 + c];
    Wa0[t] = s;
  } else if (t < OFF2){
    int u = t - OFF1;
    int i = u / 512, r = u % 512, k = r >> 3, j = r & 7, h = j & 3;
    const float* a = ((j < 4) ? gas : gad) + (size_t)i*256;
    float s = 0.f;
    for (int c = 0; c < 64; c++) s += gW[(size_t)i*16384 + k*256 + h*64 + c] * a[h*64 + c];
    Wa[u] = s;
  } else if (t < OFF3){
    int u = t - OFF2;           // u = k*64 + j, k = h*9+c
    int k = u >> 6, j = u & 63;
    int h = k / 9, c = k - h*9;
    Wstk0[u] = 0.25f * g0W[c*256 + h*64 + j];
  } else if (t < OFF4){
    int u = t - OFF3;           // u = i*16384 + k*64 + j, k = h*64+c
    int i = u >> 14, r = u & 16383;
    int k = r >> 6, j = r & 63;
    int h = k >> 6, c = k & 63;
    Wstk[u] = 0.25f * gW[(size_t)i*16384 + c*256 + h*64 + j];
  }
}

// ---------------- logits: lg[n*8+j] = hin[n,:] @ Wa[:,j] ----------------
template<int K>
__global__ __launch_bounds__(256) void k_logits(const float* __restrict__ hin, const float* __restrict__ Wa,
                                                float* __restrict__ lg){
  int idx = blockIdx.x*256 + threadIdx.x;
  int node = idx >> 3, j = idx & 7;
  if (node >= NN) return;
  const float* r = hin + (size_t)node*K;
  float s = 0.f;
  if constexpr ((K & 3) == 0){
    #pragma unroll
    for (int k4 = 0; k4 < K; k4 += 4){
      float4 v = *(const float4*)(r + k4);
      s += v.x*Wa[(k4+0)*8+j] + v.y*Wa[(k4+1)*8+j] + v.z*Wa[(k4+2)*8+j] + v.w*Wa[(k4+3)*8+j];
    }
  } else {
    #pragma unroll
    for (int k = 0; k < K; k++) s += r[k] * Wa[k*8 + j];
  }
  lg[(size_t)node*8 + j] = s;
}

// ---------------- aggregate RAW features per head (wave per node) ----------------
template<int KF>
__global__ __launch_bounds__(256) void k_aggA(const float* __restrict__ hin, const float* __restrict__ lg,
     const int* __restrict__ rp, const int* __restrict__ col, float* __restrict__ agg){
  int node = (blockIdx.x*256 + threadIdx.x) >> 6;
  int lane = threadIdx.x & 63;
  if (node >= NN) return;
  node = __builtin_amdgcn_readfirstlane(node);
  int rb = rp[node], re = rp[node+1];
  float4 esn = *(const float4*)(lg + (size_t)node*8);
  float4 edt = *(const float4*)(lg + (size_t)node*8 + 4);
  float edn[4] = {edt.x, edt.y, edt.z, edt.w};

  float den[4], acc[4];
  {
    float xv = (lane < KF) ? hin[(size_t)node*KF + lane] : 0.f;
    float a[4] = {esn.x, esn.y, esn.z, esn.w};
    #pragma unroll
    for (int h = 0; h < 4; h++){
      float ex = __expf(lrelu(a[h] + edn[h]));
      den[h] = ex; acc[h] = ex * xv;
    }
  }

  int e = rb;
  if (e < re){
    int sA = col[e];
    float4 tA = *(const float4*)(lg + (size_t)sA*8);
    float xA = (lane < KF) ? hin[(size_t)sA*KF + lane] : 0.f;
    for (; e < re; ){
      int en = e + 1;
      int sB = (en < re) ? col[en] : sA;
      float4 tB = *(const float4*)(lg + (size_t)sB*8);
      float xB = (lane < KF) ? hin[(size_t)sB*KF + lane] : 0.f;
      float ex0 = __expf(lrelu(tA.x + edn[0])); den[0] += ex0; acc[0] += ex0 * xA;
      float ex1 = __expf(lrelu(tA.y + edn[1])); den[1] += ex1; acc[1] += ex1 * xA;
      float ex2 = __expf(lrelu(tA.z + edn[2])); den[2] += ex2; acc[2] += ex2 * xA;
      float ex3 = __expf(lrelu(tA.w + edn[3])); den[3] += ex3; acc[3] += ex3 * xA;
      tA = tB; xA = xB;
      e = en;
    }
  }

  if (lane < KF){
    float* ap = agg + (size_t)node*(4*KF) + lane;
    #pragma unroll
    for (int h = 0; h < 4; h++) ap[h*KF] = acc[h] / den[h];
  }
}

// ---------------- transform + epilogue: hout = agg @ Ws (+bias, BN, ELU, +res) ----------------
// 64 nodes x 64 cols per block; thread (r=t>>4, c2=t&15) owns nodes 4r..4r+3 x cols 4c2..4c2+3.
// K chunked at CH; x-tile and W-tile both staged in LDS, all hot reads ds_read_b128,
// strides chosen (68, 44) == 4 mod 32 -> even bank distribution.
template<int KK>
__global__ __launch_bounds__(256) void k_gemmB(const float* __restrict__ agg, const float* __restrict__ Ws,
    const float* __restrict__ bias, const float* __restrict__ gma, const float* __restrict__ bta,
    const float* __restrict__ mea, const float* __restrict__ var,
    const float* __restrict__ hres, float* __restrict__ hout){
  constexpr int CH   = (KK == 256) ? 64 : 36;
  constexpr int NCH  = KK / CH;
  constexpr int XSTR = (KK == 256) ? 68 : 44;
  constexpr int RF4  = CH / 4;               // float4s per node-row chunk (16 or 9)
  __shared__ float xs[64*68];
  __shared__ float ws[64*68];
  int t = threadIdx.x;
  int base = blockIdx.x * 64;
  int r = t >> 4, c2 = t & 15;
  float acc[4][4];
  #pragma unroll
  for (int i = 0; i < 4; i++)
    #pragma unroll
    for (int u = 0; u < 4; u++) acc[i][u] = 0.f;

  for (int ch = 0; ch < NCH; ch++){
    if (ch) __syncthreads();
    // stage x chunk: 64 nodes x CH k (float4 coalesced)
    for (int i = t; i < 64*RF4; i += 256){
      int nd = i / RF4, kk = i - nd*RF4;
      float4 v = {0.f, 0.f, 0.f, 0.f};
      if (base + nd < NN) v = *(const float4*)(agg + (size_t)(base+nd)*KK + ch*CH + kk*4);
      *(float4*)(xs + nd*XSTR + kk*4) = v;
    }
    // stage W chunk: CH k x 64 cols (k-major)
    for (int i = t; i < CH*16; i += 256){
      int k = i >> 4, c4 = i & 15;
      float4 v = *(const float4*)(Ws + (size_t)(ch*CH + k)*64 + c4*4);
      *(float4*)(ws + k*68 + c4*4) = v;
    }
    __syncthreads();
    #pragma unroll 2
    for (int k4 = 0; k4 < CH; k4 += 4){
      float4 xv[4], wv[4];
      #pragma unroll
      for (int i = 0; i < 4; i++) xv[i] = *(const float4*)(xs + (4*r+i)*XSTR + k4);
      #pragma unroll
      for (int u = 0; u < 4; u++) wv[u] = *(const float4*)(ws + (k4+u)*68 + 4*c2);
      #pragma unroll
      for (int i = 0; i < 4; i++){
        float xr[4] = {xv[i].x, xv[i].y, xv[i].z, xv[i].w};
        #pragma unroll
        for (int u = 0; u < 4; u++){
          acc[i][0] += xr[u]*wv[u].x;
          acc[i][1] += xr[u]*wv[u].y;
          acc[i][2] += xr[u]*wv[u].z;
          acc[i][3] += xr[u]*wv[u].w;
        }
      }
    }
  }

  // fused epilogue: bias + BN + ELU + residual, direct coalesced float4 stores
  int cb = 4*c2;
  float4 bi = *(const float4*)(bias + cb);
  float4 gm = *(const float4*)(gma + cb);
  float4 bt = *(const float4*)(bta + cb);
  float4 me = *(const float4*)(mea + cb);
  float4 va = *(const float4*)(var + cb);
  float sc0 = rsqrtf(va.x + 1e-5f)*gm.x, sc1 = rsqrtf(va.y + 1e-5f)*gm.y;
  float sc2 = rsqrtf(va.z + 1e-5f)*gm.z, sc3 = rsqrtf(va.w + 1e-5f)*gm.w;
  #pragma unroll
  for (int i = 0; i < 4; i++){
    int node = base + 4*r + i;
    if (node < NN){
      float o0 = (acc[i][0] + bi.x - me.x)*sc0 + bt.x;
      float o1 = (acc[i][1] + bi.y - me.y)*sc1 + bt.y;
      float o2 = (acc[i][2] + bi.z - me.z)*sc2 + bt.z;
      float o3 = (acc[i][3] + bi.w - me.w)*sc3 + bt.w;
      o0 = o0 > 0.f ? o0 : (__expf(o0) - 1.f);
      o1 = o1 > 0.f ? o1 : (__expf(o1) - 1.f);
      o2 = o2 > 0.f ? o2 : (__expf(o2) - 1.f);
      o3 = o3 > 0.f ? o3 : (__expf(o3) - 1.f);
      if (hres){
        float4 rv = *(const float4*)(hres + (size_t)node*64 + cb);
        o0 += rv.x; o1 += rv.y; o2 += rv.z; o3 += rv.w;
      }
      float4 st = {o0, o1, o2, o3};
      *(float4*)(hout + (size_t)node*64 + cb) = st;
    }
  }
}

// ---------------- pooling ----------------
__global__ __launch_bounds__(64) void k_pool(const float* __restrict__ h, const int* __restrict__ gstart,
                                             float* __restrict__ pooled){
  int g = blockIdx.x; int lane = threadIdx.x;
  int beg = gstart[g], end = gstart[g+1];
  float acc = 0.f;
  for (int n = beg; n < end; n++) acc += h[(size_t)n*64 + lane];
  float cnt = (float)(end - beg);
  pooled[(size_t)g*64 + lane] = acc / fmaxf(cnt, 1.f);
}

// ---------------- output MLP ----------------
__global__ __launch_bounds__(256) void k_mlp(const float* __restrict__ pooled, const float* __restrict__ W1,
                                             const float* __restrict__ b1, const float* __restrict__ W2,
                                             const float* __restrict__ b2, float* __restrict__ out){
  int g = blockIdx.x*256 + threadIdx.x;
  if (g >= GG) return;
  const float* p = pooled + (size_t)g*64;
  float o = 0.f;
  for (int j = 0; j < 32; j++){
    float z = b1[j];
    for (int c = 0; c < 64; c++) z += p[c] * W1[c*32 + j];
    z = z > 0.f ? z : (__expf(z) - 1.f);
    o += z * W2[j];
  }
  out[g] = o + b2[0];
}

extern "C" void kernel_launch(void* const* d_in, const int* in_sizes, int n_in,
                              void* d_out, int out_size, void* d_ws, size_t ws_size,
                              hipStream_t stream) {
  const float* x    = (const float*)d_in[0];
  const int*   ei   = (const int*)d_in[1];
  const int*   batch= (const int*)d_in[2];
  const float* g0W  = (const float*)d_in[3];
  const float* g0as = (const float*)d_in[4];
  const float* g0ad = (const float*)d_in[5];
  const float* g0b  = (const float*)d_in[6];
  const float* bn0g = (const float*)d_in[7];
  const float* bn0b = (const float*)d_in[8];
  const float* bn0m = (const float*)d_in[9];
  const float* bn0v = (const float*)d_in[10];
  const float* gW   = (const float*)d_in[11];
  const float* gas  = (const float*)d_in[12];
  const float* gad  = (const float*)d_in[13];
  const float* gb   = (const float*)d_in[14];
  const float* bng  = (const float*)d_in[15];
  const float* bnb  = (const float*)d_in[16];
  const float* bnm  = (const float*)d_in[17];
  const float* bnv  = (const float*)d_in[18];
  const float* W1   = (const float*)d_in[19];
  const float* b1   = (const float*)d_in[20];
  const float* W2   = (const float*)d_in[21];
  const float* b2   = (const float*)d_in[22];
  float* out = (float*)d_out;
  (void)in_sizes; (void)n_in; (void)out_size; (void)ws_size;

  char* base = (char*)d_ws; size_t off = 0;
  auto alloc = [&](size_t b)->void*{ void* p = base + off; off = (off + b + 255) & ~(size_t)255; return p; };
  float* agg    = (float*)alloc((size_t)NN*256*4);   // 153.6 MB ([N,36] for layer 0)
  float* h_cur  = (float*)alloc((size_t)NN*64*4);    // 38.4 MB
  float* lg     = (float*)alloc((size_t)NN*8*4);     // 4.8 MB
  int*   deg    = (int*)alloc((size_t)NN*4);
  int*   fill   = (int*)alloc((size_t)NN*4);
  int*   rp     = (int*)alloc((size_t)(NN+1)*4);
  int*   col    = (int*)alloc((size_t)EE*4);
  int*   bsum   = (int*)alloc(1024*4);
  int*   gstart = (int*)alloc((size_t)(GG+1)*4);
  float* pooled = (float*)alloc((size_t)GG*64*4);
  float* Wa0    = (float*)alloc((size_t)72*4);
  float* Wa     = (float*)alloc((size_t)1536*4);
  float* Wstk0  = (float*)alloc((size_t)2304*4);
  float* Wstk   = (float*)alloc((size_t)49152*4);

  const int* esrc = ei;
  const int* edst = ei + EE;

  hipMemsetAsync(deg, 0, (size_t)NN*4, stream);
  hipMemsetAsync(fill, 0, (size_t)NN*4, stream);

  int nb1 = (NN + 255)/256;
  k_count<<<(EE+255)/256, 256, 0, stream>>>(edst, deg);
  k_scan1<<<nb1, 256, 0, stream>>>(deg, rp, bsum);
  k_scan2<<<1, 1024, 0, stream>>>(bsum, nb1);
  k_scan3<<<nb1, 256, 0, stream>>>(rp, bsum);
  k_fill<<<(EE+255)/256, 256, 0, stream>>>(esrc, edst, rp, fill, col);
  k_gstart<<<(GG+256)/256, 256, 0, stream>>>(batch, gstart);
  k_fold<<<208, 256, 0, stream>>>(g0W, g0as, g0ad, gW, gas, gad, Wa0, Wa, Wstk0, Wstk);

  int nlog  = (NN*8 + 255)/256;   // 4688
  int nwave = NN/4;               // 37500
  int ngB   = (NN + 63)/64;       // 2344

  // layer 0
  k_logits<INF><<<nlog, 256, 0, stream>>>(x, Wa0, lg);
  k_aggA<INF><<<nwave, 256, 0, stream>>>(x, lg, rp, col, agg);
  k_gemmB<4*INF><<<ngB, 256, 0, stream>>>(agg, Wstk0, g0b, bn0g, bn0b, bn0m, bn0v,
                                          nullptr, h_cur);
  // layers 1..3
  for (int i = 0; i < 3; i++){
    k_logits<CC><<<nlog, 256, 0, stream>>>(h_cur, Wa + (size_t)i*512, lg);
    k_aggA<CC><<<nwave, 256, 0, stream>>>(h_cur, lg, rp, col, agg);
    k_gemmB<256><<<ngB, 256, 0, stream>>>(agg, Wstk + (size_t)i*16384, gb + (size_t)i*64,
                                          bng + (size_t)i*64, bnb + (size_t)i*64,
                                          bnm + (size_t)i*64, bnv + (size_t)i*64,
                                          h_cur, h_cur);
  }

  k_pool<<<GG, 64, 0, stream>>>(h_cur, gstart, pooled);
  k_mlp<<<(GG+255)/256, 256, 0, stream>>>(pooled, W1, b1, W2, b2, out);
}